// Round 1
// baseline (532.577 us; speedup 1.0000x reference)
//
#include <hip/hip_runtime.h>

#define CC 85
#define NC 80
#define MAXGT 20
#define BSZ 64
#define IGNORE_T 0.5f
#define CHUNK 1024

// ws layout (bytes):
//   rows : float[192][20][85]          @ 0
//   keys : u64  [192][20]              @ ROWS_B
//   noobj: float[192]                  @ ROWS_B+KEYS_B
//   cnt  : int  [192]                  @ ROWS_B+KEYS_B+NOOBJ_B
#define ROWS_B  (192u*MAXGT*CC*4u)      /* 1,305,600 */
#define KEYS_B  (192u*MAXGT*8u)         /*    30,720 */
#define NOOBJ_B (192u*4u)               /*       768 */

// ANCH_REV[l] = ANCHORS[2-l]
__constant__ float d_anch[3][3][2] = {
  {{0.2788f,0.2163f},{0.375f,0.476f},{0.8966f,0.7837f}},  // scale 0, lsz=13
  {{0.0721f,0.1466f},{0.149f,0.1082f},{0.1418f,0.2861f}}, // scale 1, lsz=26
  {{0.024f,0.0313f},{0.0385f,0.0721f},{0.0793f,0.0553f}}, // scale 2, lsz=52
};
__constant__ int d_lsz[3] = {13,26,52};

__device__ __forceinline__ float sigmoidf(float x){ return 1.0f/(1.0f+__expf(-x)); }
__device__ __forceinline__ float bcef(float p, float t){
  p = fminf(fmaxf(p, 1e-7f), 1.0f-1e-7f);
  return -t*__logf(p) - (1.0f-t)*__logf(1.0f-p);
}
__device__ __forceinline__ float iouf(float gx,float gy,float gw,float gh,
                                      float px,float py,float pw,float ph){
  float tlx = fmaxf(gx-gw*0.5f, px-pw*0.5f);
  float tly = fmaxf(gy-gh*0.5f, py-ph*0.5f);
  float brx = fminf(gx+gw*0.5f, px+pw*0.5f);
  float bry = fminf(gy+gh*0.5f, py+ph*0.5f);
  float w = fmaxf(brx-tlx, 0.0f), h = fmaxf(bry-tly, 0.0f);
  float inter = w*h;
  float uni = gw*gh + pw*ph - inter;
  return inter / fmaxf(uni, 1e-6f);
}

// ---- kernel 0: gather GT rows per (scale,sample); init accumulators ----
__global__ void k_gather(const float* __restrict__ t0, const float* __restrict__ t1,
                         const float* __restrict__ t2,
                         float* __restrict__ ws_rows, unsigned long long* __restrict__ ws_keys,
                         float* __restrict__ ws_noobj, int* __restrict__ ws_cnt,
                         float* __restrict__ out){
  int b = blockIdx.x, s = blockIdx.y;
  int lsz = d_lsz[s], N = 3*lsz*lsz;
  const float* tgt = (s==0 ? t0 : (s==1 ? t1 : t2)) + (size_t)b*N*CC;
  int slot = s*BSZ + b;
  int tid = threadIdx.x;
  __shared__ int cnt;
  __shared__ int pos[MAXGT];
  if(tid==0) cnt = 0;
  if(slot==0 && tid==0) out[0] = 0.0f;
  if(tid<MAXGT) ws_keys[slot*MAXGT+tid] = 0ull;
  if(tid==0) ws_noobj[slot] = 0.0f;
  __syncthreads();
  // strided scan of conf column (targets are ~all-zero; <=20 hits)
  for(int n=tid; n<N; n+=blockDim.x){
    float c4 = tgt[(size_t)n*CC + 4];
    if(c4 > 0.5f){ int i = atomicAdd(&cnt,1); if(i<MAXGT) pos[i]=n; }
  }
  __syncthreads();
  int G = min(cnt, MAXGT);
  if(tid==0) ws_cnt[slot] = G;
  float* rows = ws_rows + (size_t)slot*MAXGT*CC;
  for(int idx=tid; idx<MAXGT*CC; idx+=blockDim.x){
    int g = idx/CC, c = idx - g*CC;
    rows[idx] = (g<G) ? tgt[(size_t)pos[g]*CC + c] : 0.0f; // zero rows == gmask=0 rows (exactly 0 iou)
  }
}

// ---- kernel 1: per-position boxes, IoU vs 20 GTs, argmax keys + noobj sum ----
__global__ void k_main(const float* __restrict__ p0, const float* __restrict__ p1,
                       const float* __restrict__ p2,
                       const float* __restrict__ ws_rows,
                       unsigned long long* __restrict__ ws_keys,
                       float* __restrict__ ws_noobj){
  int s = blockIdx.z, b = blockIdx.y;
  int lsz = d_lsz[s], lsz2 = lsz*lsz, N = 3*lsz2;
  int n0 = blockIdx.x*CHUNK;
  if(n0 >= N) return;
  int slot = s*BSZ + b;
  const float* pred = (s==0 ? p0 : (s==1 ? p1 : p2)) + (size_t)b*3*CC*lsz2;
  int tid = threadIdx.x;
  __shared__ float gx[MAXGT], gy[MAXGT], gw[MAXGT], gh[MAXGT];
  if(tid < MAXGT){
    const float* r = ws_rows + ((size_t)slot*MAXGT + tid)*CC;
    gx[tid]=r[0]; gy[tid]=r[1]; gw[tid]=r[2]; gh[tid]=r[3];
  }
  __syncthreads();
  unsigned long long key[MAXGT];
  #pragma unroll
  for(int g=0; g<MAXGT; g++) key[g] = 0ull;
  float noobj = 0.0f;
  float inv = 1.0f/(float)lsz;
  float aw0=d_anch[s][0][0], ah0=d_anch[s][0][1];
  float aw1=d_anch[s][1][0], ah1=d_anch[s][1][1];
  float aw2=d_anch[s][2][0], ah2=d_anch[s][2][1];
  int nend = min(n0+CHUNK, N);
  for(int n=n0+tid; n<nend; n+=blockDim.x){
    int a = n/lsz2, rem = n - a*lsz2;
    int i = rem/lsz, j = rem - i*lsz;
    const float* base = pred + (size_t)a*CC*lsz2 + rem;
    float q0 = base[0];
    float q1 = base[(size_t)lsz2];
    float q2 = base[2*(size_t)lsz2];
    float q3 = base[3*(size_t)lsz2];
    float q4 = base[4*(size_t)lsz2];
    float aw = (a==0)?aw0:((a==1)?aw1:aw2);
    float ah = (a==0)?ah0:((a==1)?ah1:ah2);
    float px = ((float)j + sigmoidf(q0))*inv;
    float py = ((float)i + sigmoidf(q1))*inv;
    float pw = aw*__expf(q2);
    float ph = ah*__expf(q3);
    float maxiou = 0.0f;
    unsigned int ninv = ~(unsigned int)n; // larger == smaller n (tie-break: first index)
    #pragma unroll
    for(int g=0; g<MAXGT; g++){
      float io = iouf(gx[g],gy[g],gw[g],gh[g], px,py,pw,ph);
      maxiou = fmaxf(maxiou, io);
      unsigned long long k = ((unsigned long long)__float_as_uint(io) << 32) | (unsigned long long)ninv;
      key[g] = (k > key[g]) ? k : key[g];
    }
    if(maxiou < IGNORE_T) noobj += bcef(sigmoidf(q4), 0.0f);
  }
  // per-wave reduce, then global atomics
  #pragma unroll
  for(int g=0; g<MAXGT; g++){
    unsigned long long k = key[g];
    for(int off=32; off>0; off>>=1){
      unsigned long long o = __shfl_down(k, off, 64);
      k = (o > k) ? o : k;
    }
    if((tid & 63) == 0) atomicMax(&ws_keys[slot*MAXGT+g], k);
  }
  for(int off=32; off>0; off>>=1) noobj += __shfl_down(noobj, off, 64);
  if((tid & 63) == 0) atomicAdd(&ws_noobj[slot], noobj);
}

// ---- kernel 2: per-GT reg/cls/conf losses + deduped noobj correction ----
__global__ void k_final(const float* __restrict__ p0, const float* __restrict__ p1,
                        const float* __restrict__ p2,
                        const float* __restrict__ ws_rows,
                        const unsigned long long* __restrict__ ws_keys,
                        const float* __restrict__ ws_noobj, const int* __restrict__ ws_cnt,
                        float* __restrict__ out){
  int b = blockIdx.x, s = blockIdx.y;
  int lsz = d_lsz[s], lsz2 = lsz*lsz;
  int slot = s*BSZ + b;
  const float* pred = (s==0 ? p0 : (s==1 ? p1 : p2)) + (size_t)b*3*CC*lsz2;
  const float* rows = ws_rows + (size_t)slot*MAXGT*CC;
  int tid = threadIdx.x;
  __shared__ int G_s;
  __shared__ int bn[MAXGT];
  if(tid==0) G_s = ws_cnt[slot];
  __syncthreads();
  int G = G_s;
  if(tid < G){
    unsigned long long k = ws_keys[slot*MAXGT + tid];
    bn[tid] = (int)(~(unsigned int)(k & 0xffffffffull));
  }
  __syncthreads();
  float loss = 0.0f;
  float inv = 1.0f/(float)lsz;
  if(tid < G){
    int n = bn[tid];
    int a = n/lsz2, rem = n - a*lsz2, i = rem/lsz, j = rem - i*lsz;
    const float* base = pred + (size_t)a*CC*lsz2 + rem;
    float q0 = base[0];
    float q1 = base[(size_t)lsz2];
    float q2 = base[2*(size_t)lsz2];
    float q3 = base[3*(size_t)lsz2];
    float q4 = base[4*(size_t)lsz2];
    float px = ((float)j + sigmoidf(q0))*inv;
    float py = ((float)i + sigmoidf(q1))*inv;
    float pw = d_anch[s][a][0]*__expf(q2);
    float ph = d_anch[s][a][1]*__expf(q3);
    const float* r = rows + tid*CC;
    float dx=px-r[0], dy=py-r[1], dw=pw-r[2], dh=ph-r[3];
    loss += (dx*dx + dy*dy + dw*dw + dh*dh) * (2.0f - r[2]*r[3]);   // reg
    loss += bcef(sigmoidf(q4), 1.0f);                               // conf (obj)
    // noobj correction: subtract bce(conf,0) once per UNIQUE best index
    bool first = true;
    for(int g2=0; g2<tid; g2++) if(bn[g2]==n) first=false;
    if(first){
      float maxiou = 0.0f;
      for(int g2=0; g2<MAXGT; g2++){
        const float* r2 = rows + g2*CC;
        maxiou = fmaxf(maxiou, iouf(r2[0],r2[1],r2[2],r2[3], px,py,pw,ph));
      }
      if(maxiou < IGNORE_T) loss -= bcef(sigmoidf(q4), 0.0f);
    }
  }
  // class loss: G*80 terms spread over the block
  for(int idx=tid; idx<G*NC; idx+=blockDim.x){
    int g = idx/NC, c = idx - g*NC;
    int n = bn[g];
    int a = n/lsz2, rem = n - a*lsz2;
    float q = pred[(size_t)a*CC*lsz2 + (size_t)(5+c)*lsz2 + rem];
    loss += bcef(sigmoidf(q), rows[g*CC + 5 + c]);
  }
  if(tid==0) loss += ws_noobj[slot];
  // block reduce (4 waves)
  __shared__ float wsum[4];
  for(int off=32; off>0; off>>=1) loss += __shfl_down(loss, off, 64);
  if((tid & 63) == 0) wsum[tid>>6] = loss;
  __syncthreads();
  if(tid==0) atomicAdd(out, wsum[0]+wsum[1]+wsum[2]+wsum[3]);
}

extern "C" void kernel_launch(void* const* d_in, const int* in_sizes, int n_in,
                              void* d_out, int out_size, void* d_ws, size_t ws_size,
                              hipStream_t stream) {
  // setup_inputs() dict order: pred0, targets0, pred1, targets1, pred2, targets2
  const float* p0 = (const float*)d_in[0];
  const float* t0 = (const float*)d_in[1];
  const float* p1 = (const float*)d_in[2];
  const float* t1 = (const float*)d_in[3];
  const float* p2 = (const float*)d_in[4];
  const float* t2 = (const float*)d_in[5];
  float* out = (float*)d_out;
  char* ws = (char*)d_ws;
  float*              ws_rows  = (float*)(ws);
  unsigned long long* ws_keys  = (unsigned long long*)(ws + ROWS_B);
  float*              ws_noobj = (float*)(ws + ROWS_B + KEYS_B);
  int*                ws_cnt   = (int*)(ws + ROWS_B + KEYS_B + NOOBJ_B);

  k_gather<<<dim3(BSZ,3), 256, 0, stream>>>(t0,t1,t2, ws_rows, ws_keys, ws_noobj, ws_cnt, out);
  k_main  <<<dim3(8,BSZ,3), 256, 0, stream>>>(p0,p1,p2, ws_rows, ws_keys, ws_noobj);
  k_final <<<dim3(BSZ,3), 256, 0, stream>>>(p0,p1,p2, ws_rows, ws_keys, ws_noobj, ws_cnt, out);
}

// Round 2
// 417.538 us; speedup vs baseline: 1.2755x; 1.2755x over previous
//
#include <hip/hip_runtime.h>

#define CC 85
#define NC 80
#define MAXGT 20
#define BSZ 64
#define IGNORE_T 0.5f
#define CHUNK 1024

// ws layout (bytes):
//   rows : float[192][20][85]          @ 0
//   keys : u64  [192][20]              @ ROWS_B
//   noobj: float[192]                  @ ROWS_B+KEYS_B
//   cnt  : int  [192]                  @ ROWS_B+KEYS_B+NOOBJ_B
#define ROWS_B  (192u*MAXGT*CC*4u)      /* 1,305,600 */
#define KEYS_B  (192u*MAXGT*8u)         /*    30,720 */
#define NOOBJ_B (192u*4u)               /*       768 */

// ANCH_REV[l] = ANCHORS[2-l]
__constant__ float d_anch[3][3][2] = {
  {{0.2788f,0.2163f},{0.375f,0.476f},{0.8966f,0.7837f}},  // scale 0, lsz=13
  {{0.0721f,0.1466f},{0.149f,0.1082f},{0.1418f,0.2861f}}, // scale 1, lsz=26
  {{0.024f,0.0313f},{0.0385f,0.0721f},{0.0793f,0.0553f}}, // scale 2, lsz=52
};
__constant__ int d_lsz[3] = {13,26,52};

__device__ __forceinline__ float sigmoidf(float x){ return 1.0f/(1.0f+__expf(-x)); }
__device__ __forceinline__ float bcef(float p, float t){
  p = fminf(fmaxf(p, 1e-7f), 1.0f-1e-7f);
  return -t*__logf(p) - (1.0f-t)*__logf(1.0f-p);
}
__device__ __forceinline__ float iouf(float gx,float gy,float gw,float gh,
                                      float px,float py,float pw,float ph){
  float tlx = fmaxf(gx-gw*0.5f, px-pw*0.5f);
  float tly = fmaxf(gy-gh*0.5f, py-ph*0.5f);
  float brx = fminf(gx+gw*0.5f, px+pw*0.5f);
  float bry = fminf(gy+gh*0.5f, py+ph*0.5f);
  float w = fmaxf(brx-tlx, 0.0f), h = fmaxf(bry-tly, 0.0f);
  float inter = w*h;
  float uni = gw*gh + pw*ph - inter;
  return inter / fmaxf(uni, 1e-6f);
}

// ---- kernel 0: gather GT rows per (scale,sample); init accumulators ----
// 1024 threads/block: the conf-column scan is a latency-bound strided read
// (1 float per 340B); 16 waves/block quadruples loads-in-flight vs 256.
__global__ __launch_bounds__(1024)
void k_gather(const float* __restrict__ t0, const float* __restrict__ t1,
              const float* __restrict__ t2,
              float* __restrict__ ws_rows, unsigned long long* __restrict__ ws_keys,
              float* __restrict__ ws_noobj, int* __restrict__ ws_cnt,
              float* __restrict__ out){
  int b = blockIdx.x, s = blockIdx.y;
  int lsz = d_lsz[s], N = 3*lsz*lsz;
  const float* tgt = (s==0 ? t0 : (s==1 ? t1 : t2)) + (size_t)b*N*CC;
  int slot = s*BSZ + b;
  int tid = threadIdx.x;
  __shared__ int cnt;
  __shared__ int pos[MAXGT];
  if(tid==0) cnt = 0;
  if(slot==0 && tid==0) out[0] = 0.0f;
  if(tid<MAXGT) ws_keys[slot*MAXGT+tid] = 0ull;
  if(tid==0) ws_noobj[slot] = 0.0f;
  __syncthreads();
  // strided scan of conf column (targets are ~all-zero; <=20 hits)
  for(int n=tid; n<N; n+=blockDim.x){
    float c4 = tgt[(size_t)n*CC + 4];
    if(c4 > 0.5f){ int i = atomicAdd(&cnt,1); if(i<MAXGT) pos[i]=n; }
  }
  __syncthreads();
  int G = min(cnt, MAXGT);
  if(tid==0) ws_cnt[slot] = G;
  float* rows = ws_rows + (size_t)slot*MAXGT*CC;
  for(int idx=tid; idx<MAXGT*CC; idx+=blockDim.x){
    int g = idx/CC, c = idx - g*CC;
    rows[idx] = (g<G) ? tgt[(size_t)pos[g]*CC + c] : 0.0f; // zero rows == gmask=0 rows (0 iou)
  }
}

// ---- kernel 1: per-position boxes, IoU vs 20 GTs, argmax keys + noobj sum ----
// __launch_bounds__(256,2): allow up to ~256 VGPRs so the 20 x u64 key array
// stays in registers. R1 post-mortem: default heuristic capped at 64 VGPRs and
// spilled keys to scratch -> 188 MB of HBM scratch traffic, 190 us.
__global__ __launch_bounds__(256, 2)
void k_main(const float* __restrict__ p0, const float* __restrict__ p1,
            const float* __restrict__ p2,
            const float* __restrict__ ws_rows,
            unsigned long long* __restrict__ ws_keys,
            float* __restrict__ ws_noobj){
  int s = blockIdx.z, b = blockIdx.y;
  int lsz = d_lsz[s], lsz2 = lsz*lsz, N = 3*lsz2;
  int n0 = blockIdx.x*CHUNK;
  if(n0 >= N) return;
  int slot = s*BSZ + b;
  const float* pred = (s==0 ? p0 : (s==1 ? p1 : p2)) + (size_t)b*3*CC*lsz2;
  int tid = threadIdx.x;
  __shared__ float gx[MAXGT], gy[MAXGT], gw[MAXGT], gh[MAXGT];
  if(tid < MAXGT){
    const float* r = ws_rows + ((size_t)slot*MAXGT + tid)*CC;
    gx[tid]=r[0]; gy[tid]=r[1]; gw[tid]=r[2]; gh[tid]=r[3];
  }
  __syncthreads();
  unsigned long long key[MAXGT];
  #pragma unroll
  for(int g=0; g<MAXGT; g++) key[g] = 0ull;
  float noobj = 0.0f;
  float inv = 1.0f/(float)lsz;
  float aw0=d_anch[s][0][0], ah0=d_anch[s][0][1];
  float aw1=d_anch[s][1][0], ah1=d_anch[s][1][1];
  float aw2=d_anch[s][2][0], ah2=d_anch[s][2][1];
  int nend = min(n0+CHUNK, N);
  for(int n=n0+tid; n<nend; n+=blockDim.x){
    int a = n/lsz2, rem = n - a*lsz2;
    int i = rem/lsz, j = rem - i*lsz;
    const float* base = pred + (size_t)a*CC*lsz2 + rem;
    float q0 = base[0];
    float q1 = base[(size_t)lsz2];
    float q2 = base[2*(size_t)lsz2];
    float q3 = base[3*(size_t)lsz2];
    float q4 = base[4*(size_t)lsz2];
    float aw = (a==0)?aw0:((a==1)?aw1:aw2);
    float ah = (a==0)?ah0:((a==1)?ah1:ah2);
    float px = ((float)j + sigmoidf(q0))*inv;
    float py = ((float)i + sigmoidf(q1))*inv;
    float pw = aw*__expf(q2);
    float ph = ah*__expf(q3);
    float maxiou = 0.0f;
    unsigned int ninv = ~(unsigned int)n; // larger == smaller n (tie-break: first index)
    #pragma unroll
    for(int g=0; g<MAXGT; g++){
      float io = iouf(gx[g],gy[g],gw[g],gh[g], px,py,pw,ph);
      maxiou = fmaxf(maxiou, io);
      unsigned long long k = ((unsigned long long)__float_as_uint(io) << 32) | (unsigned long long)ninv;
      key[g] = (k > key[g]) ? k : key[g];
    }
    if(maxiou < IGNORE_T) noobj += bcef(sigmoidf(q4), 0.0f);
  }
  // per-wave reduce, then global atomics
  #pragma unroll
  for(int g=0; g<MAXGT; g++){
    unsigned long long k = key[g];
    for(int off=32; off>0; off>>=1){
      unsigned long long o = __shfl_down(k, off, 64);
      k = (o > k) ? o : k;
    }
    if((tid & 63) == 0) atomicMax(&ws_keys[slot*MAXGT+g], k);
  }
  for(int off=32; off>0; off>>=1) noobj += __shfl_down(noobj, off, 64);
  if((tid & 63) == 0) atomicAdd(&ws_noobj[slot], noobj);
}

// ---- kernel 2: per-GT reg/cls/conf losses + deduped noobj correction ----
__global__ void k_final(const float* __restrict__ p0, const float* __restrict__ p1,
                        const float* __restrict__ p2,
                        const float* __restrict__ ws_rows,
                        const unsigned long long* __restrict__ ws_keys,
                        const float* __restrict__ ws_noobj, const int* __restrict__ ws_cnt,
                        float* __restrict__ out){
  int b = blockIdx.x, s = blockIdx.y;
  int lsz = d_lsz[s], lsz2 = lsz*lsz;
  int slot = s*BSZ + b;
  const float* pred = (s==0 ? p0 : (s==1 ? p1 : p2)) + (size_t)b*3*CC*lsz2;
  const float* rows = ws_rows + (size_t)slot*MAXGT*CC;
  int tid = threadIdx.x;
  __shared__ int G_s;
  __shared__ int bn[MAXGT];
  if(tid==0) G_s = ws_cnt[slot];
  __syncthreads();
  int G = G_s;
  if(tid < G){
    unsigned long long k = ws_keys[slot*MAXGT + tid];
    bn[tid] = (int)(~(unsigned int)(k & 0xffffffffull));
  }
  __syncthreads();
  float loss = 0.0f;
  float inv = 1.0f/(float)lsz;
  if(tid < G){
    int n = bn[tid];
    int a = n/lsz2, rem = n - a*lsz2, i = rem/lsz, j = rem - i*lsz;
    const float* base = pred + (size_t)a*CC*lsz2 + rem;
    float q0 = base[0];
    float q1 = base[(size_t)lsz2];
    float q2 = base[2*(size_t)lsz2];
    float q3 = base[3*(size_t)lsz2];
    float q4 = base[4*(size_t)lsz2];
    float px = ((float)j + sigmoidf(q0))*inv;
    float py = ((float)i + sigmoidf(q1))*inv;
    float pw = d_anch[s][a][0]*__expf(q2);
    float ph = d_anch[s][a][1]*__expf(q3);
    const float* r = rows + tid*CC;
    float dx=px-r[0], dy=py-r[1], dw=pw-r[2], dh=ph-r[3];
    loss += (dx*dx + dy*dy + dw*dw + dh*dh) * (2.0f - r[2]*r[3]);   // reg
    loss += bcef(sigmoidf(q4), 1.0f);                               // conf (obj)
    // noobj correction: subtract bce(conf,0) once per UNIQUE best index
    bool first = true;
    for(int g2=0; g2<tid; g2++) if(bn[g2]==n) first=false;
    if(first){
      float maxiou = 0.0f;
      for(int g2=0; g2<MAXGT; g2++){
        const float* r2 = rows + g2*CC;
        maxiou = fmaxf(maxiou, iouf(r2[0],r2[1],r2[2],r2[3], px,py,pw,ph));
      }
      if(maxiou < IGNORE_T) loss -= bcef(sigmoidf(q4), 0.0f);
    }
  }
  // class loss: G*80 terms spread over the block
  for(int idx=tid; idx<G*NC; idx+=blockDim.x){
    int g = idx/NC, c = idx - g*NC;
    int n = bn[g];
    int a = n/lsz2, rem = n - a*lsz2;
    float q = pred[(size_t)a*CC*lsz2 + (size_t)(5+c)*lsz2 + rem];
    loss += bcef(sigmoidf(q), rows[g*CC + 5 + c]);
  }
  if(tid==0) loss += ws_noobj[slot];
  // block reduce (4 waves)
  __shared__ float wsum[4];
  for(int off=32; off>0; off>>=1) loss += __shfl_down(loss, off, 64);
  if((tid & 63) == 0) wsum[tid>>6] = loss;
  __syncthreads();
  if(tid==0) atomicAdd(out, wsum[0]+wsum[1]+wsum[2]+wsum[3]);
}

extern "C" void kernel_launch(void* const* d_in, const int* in_sizes, int n_in,
                              void* d_out, int out_size, void* d_ws, size_t ws_size,
                              hipStream_t stream) {
  // setup_inputs() dict order: pred0, targets0, pred1, targets1, pred2, targets2
  const float* p0 = (const float*)d_in[0];
  const float* t0 = (const float*)d_in[1];
  const float* p1 = (const float*)d_in[2];
  const float* t1 = (const float*)d_in[3];
  const float* p2 = (const float*)d_in[4];
  const float* t2 = (const float*)d_in[5];
  float* out = (float*)d_out;
  char* ws = (char*)d_ws;
  float*              ws_rows  = (float*)(ws);
  unsigned long long* ws_keys  = (unsigned long long*)(ws + ROWS_B);
  float*              ws_noobj = (float*)(ws + ROWS_B + KEYS_B);
  int*                ws_cnt   = (int*)(ws + ROWS_B + KEYS_B + NOOBJ_B);

  k_gather<<<dim3(BSZ,3), 1024, 0, stream>>>(t0,t1,t2, ws_rows, ws_keys, ws_noobj, ws_cnt, out);
  k_main  <<<dim3(8,BSZ,3), 256, 0, stream>>>(p0,p1,p2, ws_rows, ws_keys, ws_noobj);
  k_final <<<dim3(BSZ,3), 256, 0, stream>>>(p0,p1,p2, ws_rows, ws_keys, ws_noobj, ws_cnt, out);
}

// Round 3
// 417.155 us; speedup vs baseline: 1.2767x; 1.0009x over previous
//
#include <hip/hip_runtime.h>

#define CC 85
#define NC 80
#define MAXGT 20
#define BSZ 64
#define IGNORE_T 0.5f
#define CHUNK 1024

// ws layout (bytes) — all zero-initialized by hipMemsetAsync:
//   pos  : int [192][20]   @ 0         (15360)
//   keys : u64 [192][20]   @ 15360     (30720)
//   noobj: float[192]      @ 46080     (768)
//   cnt  : int [192]       @ 46848     (768)
#define POS_B   (192u*MAXGT*4u)
#define KEYS_B  (192u*MAXGT*8u)
#define NOOBJ_B (192u*4u)
#define HDR_B   (POS_B + KEYS_B + NOOBJ_B + 192u*4u)   /* 47616 */

// rows per (scale): 3*lsz*lsz
#define N0 507
#define N1 2028
#define N2 8112
#define R0 (BSZ*N0)   /* 32448  */
#define R1 (BSZ*N1)   /* 129792 */
#define R2 (BSZ*N2)   /* 519168 */
#define RTOT (R0+R1+R2) /* 681408 */

// ANCH_REV[l] = ANCHORS[2-l]
__constant__ float d_anch[3][3][2] = {
  {{0.2788f,0.2163f},{0.375f,0.476f},{0.8966f,0.7837f}},  // scale 0, lsz=13
  {{0.0721f,0.1466f},{0.149f,0.1082f},{0.1418f,0.2861f}}, // scale 1, lsz=26
  {{0.024f,0.0313f},{0.0385f,0.0721f},{0.0793f,0.0553f}}, // scale 2, lsz=52
};
__constant__ int d_lsz[3] = {13,26,52};

__device__ __forceinline__ float sigmoidf(float x){ return 1.0f/(1.0f+__expf(-x)); }
__device__ __forceinline__ float bcef(float p, float t){
  p = fminf(fmaxf(p, 1e-7f), 1.0f-1e-7f);
  return -t*__logf(p) - (1.0f-t)*__logf(1.0f-p);
}
__device__ __forceinline__ float iouf(float gx,float gy,float gw,float gh,
                                      float px,float py,float pw,float ph){
  float tlx = fmaxf(gx-gw*0.5f, px-pw*0.5f);
  float tly = fmaxf(gy-gh*0.5f, py-ph*0.5f);
  float brx = fminf(gx+gw*0.5f, px+pw*0.5f);
  float bry = fminf(gy+gh*0.5f, py+ph*0.5f);
  float w = fmaxf(brx-tlx, 0.0f), h = fmaxf(bry-tly, 0.0f);
  float inter = w*h;
  float uni = gw*gh + pw*ph - inter;
  return inter / fmaxf(uni, 1e-6f);
}

// ---- kernel 0: flat conf-column scan over ALL rows of all 3 target tensors.
// One load per thread across 2662 blocks -> maximal MLP for the latency-bound
// strided read (4B of every 340B; one line per row, ~87 MB line traffic).
__device__ __forceinline__ void scan_hit(const float* __restrict__ t, int rl,
                                         int Nr, int s,
                                         int* __restrict__ ws_pos,
                                         int* __restrict__ ws_cnt){
  float c = t[(size_t)rl*CC + 4];
  if(c > 0.5f){
    int b = rl / Nr;          // Nr is a compile-time constant at each call site
    int n = rl - b*Nr;
    int slot = s*BSZ + b;
    int i = atomicAdd(&ws_cnt[slot], 1);
    if(i < MAXGT) ws_pos[slot*MAXGT + i] = n;
  }
}

__global__ __launch_bounds__(256)
void k_scan(const float* __restrict__ t0, const float* __restrict__ t1,
            const float* __restrict__ t2,
            int* __restrict__ ws_pos, int* __restrict__ ws_cnt){
  int r = blockIdx.x*256 + threadIdx.x;
  if(r < R0)            scan_hit(t0, r,        N0, 0, ws_pos, ws_cnt);
  else if(r < R0+R1)    scan_hit(t1, r-R0,     N1, 1, ws_pos, ws_cnt);
  else if(r < RTOT)     scan_hit(t2, r-R0-R1,  N2, 2, ws_pos, ws_cnt);
}

// ---- kernel 1: per-position boxes, IoU vs 20 GTs, argmax keys + noobj sum ----
// __launch_bounds__(256,2): keep the 20 x u64 key array in registers (R1
// post-mortem: default 64-VGPR cap spilled it -> 188 MB scratch traffic).
__global__ __launch_bounds__(256, 2)
void k_main(const float* __restrict__ p0, const float* __restrict__ p1,
            const float* __restrict__ p2,
            const float* __restrict__ t0, const float* __restrict__ t1,
            const float* __restrict__ t2,
            const int* __restrict__ ws_pos, const int* __restrict__ ws_cnt,
            unsigned long long* __restrict__ ws_keys,
            float* __restrict__ ws_noobj){
  int s = blockIdx.z, b = blockIdx.y;
  int lsz = d_lsz[s], lsz2 = lsz*lsz, N = 3*lsz2;
  int n0 = blockIdx.x*CHUNK;
  if(n0 >= N) return;
  int slot = s*BSZ + b;
  const float* pred = (s==0 ? p0 : (s==1 ? p1 : p2)) + (size_t)b*3*CC*lsz2;
  const float* tgt  = (s==0 ? t0 : (s==1 ? t1 : t2)) + (size_t)b*N*CC;
  int tid = threadIdx.x;
  __shared__ float gx[MAXGT], gy[MAXGT], gw[MAXGT], gh[MAXGT];
  if(tid < MAXGT){
    int G = ws_cnt[slot];
    float x=0.f,y=0.f,w=0.f,h=0.f;
    if(tid < G){
      const float* r = tgt + (size_t)ws_pos[slot*MAXGT+tid]*CC;
      x=r[0]; y=r[1]; w=r[2]; h=r[3];
    }
    gx[tid]=x; gy[tid]=y; gw[tid]=w; gh[tid]=h;
  }
  __syncthreads();
  unsigned long long key[MAXGT];
  #pragma unroll
  for(int g=0; g<MAXGT; g++) key[g] = 0ull;
  float noobj = 0.0f;
  float inv = 1.0f/(float)lsz;
  float aw0=d_anch[s][0][0], ah0=d_anch[s][0][1];
  float aw1=d_anch[s][1][0], ah1=d_anch[s][1][1];
  float aw2=d_anch[s][2][0], ah2=d_anch[s][2][1];
  int nend = min(n0+CHUNK, N);
  for(int n=n0+tid; n<nend; n+=256){
    int a = n/lsz2, rem = n - a*lsz2;
    int i = rem/lsz, j = rem - i*lsz;
    const float* base = pred + (size_t)a*CC*lsz2 + rem;
    float q0 = base[0];
    float q1 = base[(size_t)lsz2];
    float q2 = base[2*(size_t)lsz2];
    float q3 = base[3*(size_t)lsz2];
    float q4 = base[4*(size_t)lsz2];
    float aw = (a==0)?aw0:((a==1)?aw1:aw2);
    float ah = (a==0)?ah0:((a==1)?ah1:ah2);
    float px = ((float)j + sigmoidf(q0))*inv;
    float py = ((float)i + sigmoidf(q1))*inv;
    float pw = aw*__expf(q2);
    float ph = ah*__expf(q3);
    float maxiou = 0.0f;
    unsigned int ninv = ~(unsigned int)n; // larger == smaller n (tie-break: first index)
    #pragma unroll
    for(int g=0; g<MAXGT; g++){
      float io = iouf(gx[g],gy[g],gw[g],gh[g], px,py,pw,ph);
      maxiou = fmaxf(maxiou, io);
      unsigned long long k = ((unsigned long long)__float_as_uint(io) << 32) | (unsigned long long)ninv;
      key[g] = (k > key[g]) ? k : key[g];
    }
    if(maxiou < IGNORE_T) noobj += bcef(sigmoidf(q4), 0.0f);
  }
  // per-wave reduce, then global atomics
  #pragma unroll
  for(int g=0; g<MAXGT; g++){
    unsigned long long k = key[g];
    for(int off=32; off>0; off>>=1){
      unsigned long long o = __shfl_down(k, off, 64);
      k = (o > k) ? o : k;
    }
    if((tid & 63) == 0) atomicMax(&ws_keys[slot*MAXGT+g], k);
  }
  for(int off=32; off>0; off>>=1) noobj += __shfl_down(noobj, off, 64);
  if((tid & 63) == 0) atomicAdd(&ws_noobj[slot], noobj);
}

// ---- kernel 2: per-GT reg/cls/conf losses + deduped noobj correction ----
__global__ __launch_bounds__(256)
void k_final(const float* __restrict__ p0, const float* __restrict__ p1,
             const float* __restrict__ p2,
             const float* __restrict__ t0, const float* __restrict__ t1,
             const float* __restrict__ t2,
             const int* __restrict__ ws_pos, const int* __restrict__ ws_cnt,
             const unsigned long long* __restrict__ ws_keys,
             const float* __restrict__ ws_noobj,
             float* __restrict__ out){
  int b = blockIdx.x, s = blockIdx.y;
  int lsz = d_lsz[s], lsz2 = lsz*lsz, N = 3*lsz2;
  int slot = s*BSZ + b;
  const float* pred = (s==0 ? p0 : (s==1 ? p1 : p2)) + (size_t)b*3*CC*lsz2;
  const float* tgt  = (s==0 ? t0 : (s==1 ? t1 : t2)) + (size_t)b*N*CC;
  int tid = threadIdx.x;
  __shared__ int bn[MAXGT];
  __shared__ int gp[MAXGT];
  __shared__ float sx[MAXGT], sy[MAXGT], sw[MAXGT], sh[MAXGT];
  int G = ws_cnt[slot];
  if(tid < MAXGT){
    unsigned long long k = ws_keys[slot*MAXGT + tid];
    bn[tid] = (int)(~(unsigned int)(k & 0xffffffffull));
    float x=0.f,y=0.f,w=0.f,h=0.f; int p=0;
    if(tid < G){
      p = ws_pos[slot*MAXGT + tid];
      const float* r = tgt + (size_t)p*CC;
      x=r[0]; y=r[1]; w=r[2]; h=r[3];
    }
    gp[tid]=p; sx[tid]=x; sy[tid]=y; sw[tid]=w; sh[tid]=h;
  }
  __syncthreads();
  float loss = 0.0f;
  float inv = 1.0f/(float)lsz;
  if(tid < G){
    int n = bn[tid];
    int a = n/lsz2, rem = n - a*lsz2, i = rem/lsz, j = rem - i*lsz;
    const float* base = pred + (size_t)a*CC*lsz2 + rem;
    float q0 = base[0];
    float q1 = base[(size_t)lsz2];
    float q2 = base[2*(size_t)lsz2];
    float q3 = base[3*(size_t)lsz2];
    float q4 = base[4*(size_t)lsz2];
    float px = ((float)j + sigmoidf(q0))*inv;
    float py = ((float)i + sigmoidf(q1))*inv;
    float pw = d_anch[s][a][0]*__expf(q2);
    float ph = d_anch[s][a][1]*__expf(q3);
    float dx=px-sx[tid], dy=py-sy[tid], dw=pw-sw[tid], dh=ph-sh[tid];
    loss += (dx*dx + dy*dy + dw*dw + dh*dh) * (2.0f - sw[tid]*sh[tid]);  // reg
    loss += bcef(sigmoidf(q4), 1.0f);                                    // conf (obj)
    // noobj correction: subtract bce(conf,0) once per UNIQUE best index
    bool first = true;
    for(int g2=0; g2<tid; g2++) if(bn[g2]==n) first=false;
    if(first){
      float maxiou = 0.0f;
      for(int g2=0; g2<MAXGT; g2++)
        maxiou = fmaxf(maxiou, iouf(sx[g2],sy[g2],sw[g2],sh[g2], px,py,pw,ph));
      if(maxiou < IGNORE_T) loss -= bcef(sigmoidf(q4), 0.0f);
    }
  }
  // class loss: G*80 terms spread over the block
  for(int idx=tid; idx<G*NC; idx+=256){
    int g = idx/NC, c = idx - g*NC;
    int n = bn[g];
    int a = n/lsz2, rem = n - a*lsz2;
    float q = pred[(size_t)a*CC*lsz2 + (size_t)(5+c)*lsz2 + rem];
    float tcls = tgt[(size_t)gp[g]*CC + 5 + c];
    loss += bcef(sigmoidf(q), tcls);
  }
  if(tid==0) loss += ws_noobj[slot];
  // block reduce (4 waves)
  __shared__ float wsum[4];
  for(int off=32; off>0; off>>=1) loss += __shfl_down(loss, off, 64);
  if((tid & 63) == 0) wsum[tid>>6] = loss;
  __syncthreads();
  if(tid==0) atomicAdd(out, wsum[0]+wsum[1]+wsum[2]+wsum[3]);
}

extern "C" void kernel_launch(void* const* d_in, const int* in_sizes, int n_in,
                              void* d_out, int out_size, void* d_ws, size_t ws_size,
                              hipStream_t stream) {
  // setup_inputs() dict order: pred0, targets0, pred1, targets1, pred2, targets2
  const float* p0 = (const float*)d_in[0];
  const float* t0 = (const float*)d_in[1];
  const float* p1 = (const float*)d_in[2];
  const float* t1 = (const float*)d_in[3];
  const float* p2 = (const float*)d_in[4];
  const float* t2 = (const float*)d_in[5];
  float* out = (float*)d_out;
  char* ws = (char*)d_ws;
  int*                ws_pos   = (int*)(ws);
  unsigned long long* ws_keys  = (unsigned long long*)(ws + POS_B);
  float*              ws_noobj = (float*)(ws + POS_B + KEYS_B);
  int*                ws_cnt   = (int*)(ws + POS_B + KEYS_B + NOOBJ_B);

  hipMemsetAsync(ws, 0, HDR_B, stream);        // keys=0, cnt=0, noobj=0
  hipMemsetAsync(d_out, 0, sizeof(float), stream);

  k_scan <<<(RTOT+255)/256, 256, 0, stream>>>(t0,t1,t2, ws_pos, ws_cnt);
  k_main <<<dim3(8,BSZ,3), 256, 0, stream>>>(p0,p1,p2, t0,t1,t2,
                                             ws_pos, ws_cnt, ws_keys, ws_noobj);
  k_final<<<dim3(BSZ,3), 256, 0, stream>>>(p0,p1,p2, t0,t1,t2,
                                           ws_pos, ws_cnt, ws_keys, ws_noobj, out);
}

// Round 4
// 411.259 us; speedup vs baseline: 1.2950x; 1.0143x over previous
//
#include <hip/hip_runtime.h>

#define CC 85
#define NC 80
#define MAXGT 20
#define BSZ 64
#define IGNORE_T 0.5f
#define CHUNK 1024

// rows/positions per scale: 3*lsz*lsz
#define N0 507
#define N1 2028
#define N2 8112
#define R0 (BSZ*N0)   /* 32448  */
#define R1 (BSZ*N1)   /* 129792 */
#define R2 (BSZ*N2)   /* 519168 */
#define RTOT (R0+R1+R2) /* 681408 */

// ws layout (bytes) — hdr zero-initialized by hipMemsetAsync:
//   pos  : int [192][20]   @ 0
//   keys : u64 [192][20]   @ POS_B
//   noobj: float[192]      @ POS_B+KEYS_B
//   cnt  : int [192]       @ POS_B+KEYS_B+NOOBJ_B
//   box4 : float4[RTOT]    @ HDR_B          (13.7 MB total with confr)
//   confr: float [RTOT]    @ HDR_B+BOX_B
#define POS_B   (192u*MAXGT*4u)
#define KEYS_B  (192u*MAXGT*8u)
#define NOOBJ_B (192u*4u)
#define HDR_B   (POS_B + KEYS_B + NOOBJ_B + 192u*4u)   /* 47616, 16-aligned */
#define BOX_B   ((unsigned)RTOT*16u)

// ANCH_REV[l] = ANCHORS[2-l]
__constant__ float d_anch[3][3][2] = {
  {{0.2788f,0.2163f},{0.375f,0.476f},{0.8966f,0.7837f}},  // scale 0, lsz=13
  {{0.0721f,0.1466f},{0.149f,0.1082f},{0.1418f,0.2861f}}, // scale 1, lsz=26
  {{0.024f,0.0313f},{0.0385f,0.0721f},{0.0793f,0.0553f}}, // scale 2, lsz=52
};
__constant__ int d_lsz[3] = {13,26,52};

__device__ __forceinline__ float sigmoidf(float x){ return 1.0f/(1.0f+__expf(-x)); }
__device__ __forceinline__ float bcef(float p, float t){
  p = fminf(fmaxf(p, 1e-7f), 1.0f-1e-7f);
  return -t*__logf(p) - (1.0f-t)*__logf(1.0f-p);
}
__device__ __forceinline__ float iouf(float gx,float gy,float gw,float gh,
                                      float px,float py,float pw,float ph){
  float tlx = fmaxf(gx-gw*0.5f, px-pw*0.5f);
  float tly = fmaxf(gy-gh*0.5f, py-ph*0.5f);
  float brx = fminf(gx+gw*0.5f, px+pw*0.5f);
  float bry = fminf(gy+gh*0.5f, py+ph*0.5f);
  float w = fmaxf(brx-tlx, 0.0f), h = fmaxf(bry-tly, 0.0f);
  float inter = w*h;
  float uni = gw*gh + pw*ph - inter;
  return inter / fmaxf(uni, 1e-6f);
}

// ---- kernel 0: fused conf-scan + box decode. The scattered conf line
// fetches (1 line per 340B row, ~87 MB) overlap with the coalesced 5-channel
// pred reads and box math instead of serializing in separate kernels.
template<int LSZ>
__device__ __forceinline__ void scanbox_one(const float* __restrict__ tgt,
                                            const float* __restrict__ pred,
                                            int rl, int s, int gofs,
                                            int* __restrict__ ws_pos,
                                            int* __restrict__ ws_cnt,
                                            float4* __restrict__ box4,
                                            float* __restrict__ confr){
  const int L2 = LSZ*LSZ, N = 3*L2;
  int b = rl / N;                 // compile-time-constant divisors
  int n = rl - b*N;
  // conf scan (targets ~all-zero; <=20 hits/sample)
  float c = tgt[(size_t)rl*CC + 4];
  if(c > 0.5f){
    int slot = s*BSZ + b;
    int i = atomicAdd(&ws_cnt[slot], 1);
    if(i < MAXGT) ws_pos[slot*MAXGT + i] = n;
  }
  // box decode
  int a = n / L2, rem = n - a*L2;
  int ii = rem / LSZ, jj = rem - ii*LSZ;
  const float* base = pred + (size_t)b*3*CC*L2 + (size_t)a*CC*L2 + rem;
  float q0 = base[0];
  float q1 = base[L2];
  float q2 = base[2*L2];
  float q3 = base[3*L2];
  float q4 = base[4*L2];
  const float inv = 1.0f/(float)LSZ;
  float px = ((float)jj + sigmoidf(q0))*inv;
  float py = ((float)ii + sigmoidf(q1))*inv;
  float pw = d_anch[s][a][0]*__expf(q2);
  float ph = d_anch[s][a][1]*__expf(q3);
  box4[gofs + rl] = make_float4(px,py,pw,ph);
  confr[gofs + rl] = q4;
}

__global__ __launch_bounds__(256)
void k_scanbox(const float* __restrict__ t0, const float* __restrict__ t1,
               const float* __restrict__ t2,
               const float* __restrict__ p0, const float* __restrict__ p1,
               const float* __restrict__ p2,
               int* __restrict__ ws_pos, int* __restrict__ ws_cnt,
               float4* __restrict__ box4, float* __restrict__ confr){
  int r = blockIdx.x*256 + threadIdx.x;
  if(r < R0)         scanbox_one<13>(t0, p0, r,       0, 0,     ws_pos, ws_cnt, box4, confr);
  else if(r < R0+R1) scanbox_one<26>(t1, p1, r-R0,    1, R0,    ws_pos, ws_cnt, box4, confr);
  else if(r < RTOT)  scanbox_one<52>(t2, p2, r-R0-R1, 2, R0+R1, ws_pos, ws_cnt, box4, confr);
}

// ---- kernel 1: IoU vs 20 GTs from materialized boxes; block-reduced
// argmax keys + noobj sum (4x fewer atomics than per-wave).
// __launch_bounds__(256,2): keep the 20 x u64 key array in registers (R1
// post-mortem: default 64-VGPR cap spilled it -> 188 MB scratch traffic).
__global__ __launch_bounds__(256, 2)
void k_iou(const float* __restrict__ t0, const float* __restrict__ t1,
           const float* __restrict__ t2,
           const float4* __restrict__ box4, const float* __restrict__ confr,
           const int* __restrict__ ws_pos, const int* __restrict__ ws_cnt,
           unsigned long long* __restrict__ ws_keys,
           float* __restrict__ ws_noobj){
  int s = blockIdx.z, b = blockIdx.y;
  int lsz = d_lsz[s], lsz2 = lsz*lsz, N = 3*lsz2;
  int n0 = blockIdx.x*CHUNK;
  if(n0 >= N) return;
  int slot = s*BSZ + b;
  int gofs = (s==0 ? 0 : (s==1 ? R0 : R0+R1)) + b*N;
  const float* tgt = (s==0 ? t0 : (s==1 ? t1 : t2)) + (size_t)b*N*CC;
  const float4* bx = box4 + gofs;
  const float*  cf = confr + gofs;
  int tid = threadIdx.x;
  __shared__ float gx[MAXGT], gy[MAXGT], gw[MAXGT], gh[MAXGT];
  __shared__ unsigned long long lkey[4][MAXGT];
  __shared__ float lnob[4];
  if(tid < MAXGT){
    int G = ws_cnt[slot];
    float x=0.f,y=0.f,w=0.f,h=0.f;
    if(tid < G){
      const float* r = tgt + (size_t)ws_pos[slot*MAXGT+tid]*CC;
      x=r[0]; y=r[1]; w=r[2]; h=r[3];
    }
    gx[tid]=x; gy[tid]=y; gw[tid]=w; gh[tid]=h;
  }
  __syncthreads();
  unsigned long long key[MAXGT];
  #pragma unroll
  for(int g=0; g<MAXGT; g++) key[g] = 0ull;
  float noobj = 0.0f;
  int nend = min(n0+CHUNK, N);
  for(int n=n0+tid; n<nend; n+=256){
    float4 B = bx[n];
    float q4 = cf[n];
    float maxiou = 0.0f;
    unsigned int ninv = ~(unsigned int)n; // larger == smaller n (tie-break: first)
    #pragma unroll
    for(int g=0; g<MAXGT; g++){
      float io = iouf(gx[g],gy[g],gw[g],gh[g], B.x,B.y,B.z,B.w);
      maxiou = fmaxf(maxiou, io);
      unsigned long long k = ((unsigned long long)__float_as_uint(io) << 32) | (unsigned long long)ninv;
      key[g] = (k > key[g]) ? k : key[g];
    }
    if(maxiou < IGNORE_T) noobj += bcef(sigmoidf(q4), 0.0f);
  }
  // wave reduce -> LDS -> block reduce -> one atomic set per block
  int wid = tid >> 6, lane = tid & 63;
  #pragma unroll
  for(int g=0; g<MAXGT; g++){
    unsigned long long k = key[g];
    for(int off=32; off>0; off>>=1){
      unsigned long long o = __shfl_down(k, off, 64);
      k = (o > k) ? o : k;
    }
    if(lane == 0) lkey[wid][g] = k;
  }
  for(int off=32; off>0; off>>=1) noobj += __shfl_down(noobj, off, 64);
  if(lane == 0) lnob[wid] = noobj;
  __syncthreads();
  if(tid < MAXGT){
    unsigned long long k0 = lkey[0][tid] > lkey[1][tid] ? lkey[0][tid] : lkey[1][tid];
    unsigned long long k1 = lkey[2][tid] > lkey[3][tid] ? lkey[2][tid] : lkey[3][tid];
    unsigned long long k  = k0 > k1 ? k0 : k1;
    atomicMax(&ws_keys[slot*MAXGT+tid], k);
  }
  if(tid == 0) atomicAdd(&ws_noobj[slot], lnob[0]+lnob[1]+lnob[2]+lnob[3]);
}

// ---- kernel 2: per-GT reg/cls/conf losses + deduped noobj correction.
// z-split x4: class-logit gather is ~307K scattered cache lines; 768 blocks
// keep more of them in flight than 192.
__global__ __launch_bounds__(256)
void k_final(const float* __restrict__ p0, const float* __restrict__ p1,
             const float* __restrict__ p2,
             const float* __restrict__ t0, const float* __restrict__ t1,
             const float* __restrict__ t2,
             const int* __restrict__ ws_pos, const int* __restrict__ ws_cnt,
             const unsigned long long* __restrict__ ws_keys,
             const float* __restrict__ ws_noobj,
             float* __restrict__ out){
  int b = blockIdx.x, s = blockIdx.y, z = blockIdx.z;
  int lsz = d_lsz[s], lsz2 = lsz*lsz, N = 3*lsz2;
  int slot = s*BSZ + b;
  const float* pred = (s==0 ? p0 : (s==1 ? p1 : p2)) + (size_t)b*3*CC*lsz2;
  const float* tgt  = (s==0 ? t0 : (s==1 ? t1 : t2)) + (size_t)b*N*CC;
  int tid = threadIdx.x;
  __shared__ int bn[MAXGT];
  __shared__ int gp[MAXGT];
  __shared__ float sx[MAXGT], sy[MAXGT], sw[MAXGT], sh[MAXGT];
  int G = ws_cnt[slot];
  if(tid < MAXGT){
    unsigned long long k = ws_keys[slot*MAXGT + tid];
    bn[tid] = (int)(~(unsigned int)(k & 0xffffffffull));
    float x=0.f,y=0.f,w=0.f,h=0.f; int p=0;
    if(tid < G){
      p = ws_pos[slot*MAXGT + tid];
      const float* r = tgt + (size_t)p*CC;
      x=r[0]; y=r[1]; w=r[2]; h=r[3];
    }
    gp[tid]=p; sx[tid]=x; sy[tid]=y; sw[tid]=w; sh[tid]=h;
  }
  __syncthreads();
  float loss = 0.0f;
  float inv = 1.0f/(float)lsz;
  if(z == 0 && tid < G){
    int n = bn[tid];
    int a = n/lsz2, rem = n - a*lsz2, i = rem/lsz, j = rem - i*lsz;
    const float* base = pred + (size_t)a*CC*lsz2 + rem;
    float q0 = base[0];
    float q1 = base[(size_t)lsz2];
    float q2 = base[2*(size_t)lsz2];
    float q3 = base[3*(size_t)lsz2];
    float q4 = base[4*(size_t)lsz2];
    float px = ((float)j + sigmoidf(q0))*inv;
    float py = ((float)i + sigmoidf(q1))*inv;
    float pw = d_anch[s][a][0]*__expf(q2);
    float ph = d_anch[s][a][1]*__expf(q3);
    float dx=px-sx[tid], dy=py-sy[tid], dw=pw-sw[tid], dh=ph-sh[tid];
    loss += (dx*dx + dy*dy + dw*dw + dh*dh) * (2.0f - sw[tid]*sh[tid]);  // reg
    loss += bcef(sigmoidf(q4), 1.0f);                                    // conf (obj)
    // noobj correction: subtract bce(conf,0) once per UNIQUE best index
    bool first = true;
    for(int g2=0; g2<tid; g2++) if(bn[g2]==n) first=false;
    if(first){
      float maxiou = 0.0f;
      for(int g2=0; g2<MAXGT; g2++)
        maxiou = fmaxf(maxiou, iouf(sx[g2],sy[g2],sw[g2],sh[g2], px,py,pw,ph));
      if(maxiou < IGNORE_T) loss -= bcef(sigmoidf(q4), 0.0f);
    }
  }
  // class loss: G*80 terms, interleaved across the 4 z-blocks
  for(int idx = z*256 + tid; idx < G*NC; idx += 1024){
    int g = idx/NC, c = idx - g*NC;
    int n = bn[g];
    int a = n/lsz2, rem = n - a*lsz2;
    float q = pred[(size_t)a*CC*lsz2 + (size_t)(5+c)*lsz2 + rem];
    float tcls = tgt[(size_t)gp[g]*CC + 5 + c];
    loss += bcef(sigmoidf(q), tcls);
  }
  if(z == 0 && tid == 0) loss += ws_noobj[slot];
  // block reduce (4 waves)
  __shared__ float wsum[4];
  for(int off=32; off>0; off>>=1) loss += __shfl_down(loss, off, 64);
  if((tid & 63) == 0) wsum[tid>>6] = loss;
  __syncthreads();
  if(tid==0){
    float v = wsum[0]+wsum[1]+wsum[2]+wsum[3];
    if(v != 0.0f || z == 0) atomicAdd(out, v);
  }
}

extern "C" void kernel_launch(void* const* d_in, const int* in_sizes, int n_in,
                              void* d_out, int out_size, void* d_ws, size_t ws_size,
                              hipStream_t stream) {
  // setup_inputs() dict order: pred0, targets0, pred1, targets1, pred2, targets2
  const float* p0 = (const float*)d_in[0];
  const float* t0 = (const float*)d_in[1];
  const float* p1 = (const float*)d_in[2];
  const float* t1 = (const float*)d_in[3];
  const float* p2 = (const float*)d_in[4];
  const float* t2 = (const float*)d_in[5];
  float* out = (float*)d_out;
  char* ws = (char*)d_ws;
  int*                ws_pos   = (int*)(ws);
  unsigned long long* ws_keys  = (unsigned long long*)(ws + POS_B);
  float*              ws_noobj = (float*)(ws + POS_B + KEYS_B);
  int*                ws_cnt   = (int*)(ws + POS_B + KEYS_B + NOOBJ_B);
  float4*             ws_box4  = (float4*)(ws + HDR_B);
  float*              ws_confr = (float*)(ws + HDR_B + BOX_B);

  hipMemsetAsync(ws, 0, HDR_B, stream);        // pos/keys/noobj/cnt = 0
  hipMemsetAsync(d_out, 0, sizeof(float), stream);

  k_scanbox<<<(RTOT+255)/256, 256, 0, stream>>>(t0,t1,t2, p0,p1,p2,
                                                ws_pos, ws_cnt, ws_box4, ws_confr);
  k_iou    <<<dim3(8,BSZ,3), 256, 0, stream>>>(t0,t1,t2, ws_box4, ws_confr,
                                               ws_pos, ws_cnt, ws_keys, ws_noobj);
  k_final  <<<dim3(BSZ,3,4), 256, 0, stream>>>(p0,p1,p2, t0,t1,t2,
                                               ws_pos, ws_cnt, ws_keys, ws_noobj, out);
}